// Round 8
// baseline (114.433 us; speedup 1.0000x reference)
//
#include <hip/hip_runtime.h>
#include <math.h>

// Neural-ODE RK45 — round 8: 16 lanes / 2 packed elements, ZERO LDS.
// r2-r7 evidence: plateau ~30-40 us from DS-pipe occupancy + VALU issue +
// exposed latency. This round removes the DS pipe from the loop entirely:
// the h1 all-gather is a 4-stage DPP butterfly of INVOLUTIONS only
// (quad_perm xor1=0xB1, xor2=0x4E, row_half_mirror=xor7=0x141,
// row_mirror=xor15=0x140), 60 v_mov_dpp on the VALU pipe. Slot i of the
// gathered array arrives from lane m ^ P[i], P={0,1,2,3,7,6,5,4,
// 15,14,13,12,8,9,10,11}; the w2 register slices are loaded pre-permuted
// to match, so layer-2 is 64 pk-FMAs (32/element). Elements ride pk
// halves everywhere (layer1/3, glue, controller) as in r6. FSAL kept.
// 131072 threads = 2048 waves = 2/SIMD on all 1024 SIMDs; no LDS, no
// lgkmcnt waits -> the only pipes are VALU + 60%-hidden DPP chain.

#define MAXS 96

typedef float v2f __attribute__((ext_vector_type(2)));

static __device__ __forceinline__ v2f splat(float s){ v2f v; v.x=s; v.y=s; return v; }
static __device__ __forceinline__ v2f vfma(v2f a, v2f b, v2f c){ return __builtin_elementwise_fma(a,b,c); }
static __device__ __forceinline__ v2f vrelu(v2f a){ return __builtin_elementwise_max(a, splat(0.0f)); }
static __device__ __forceinline__ v2f slo(v2f v){ return __builtin_shufflevector(v,v,0,0); }
static __device__ __forceinline__ v2f shi(v2f v){ return __builtin_shufflevector(v,v,1,1); }

template<int CTRL>
static __device__ __forceinline__ float dppf(float x){
    return __int_as_float(__builtin_amdgcn_update_dpp(0, __float_as_int(x), CTRL, 0xF, 0xF, false));
}
// 16-lane all-reduce sum (involutive stages; bitwise-uniform result).
static __device__ __forceinline__ v2f dpp_allreduce16(v2f p){
    p.x += dppf<0xB1>(p.x);  p.y += dppf<0xB1>(p.y);
    p.x += dppf<0x4E>(p.x);  p.y += dppf<0x4E>(p.y);
    p.x += dppf<0x141>(p.x); p.y += dppf<0x141>(p.y);
    p.x += dppf<0x140>(p.x); p.y += dppf<0x140>(p.y);
    return p;
}

__global__ __launch_bounds__(256, 2) void node_kernel(
    const float* __restrict__ x, const float* __restrict__ samples,
    const float* __restrict__ w1, const float* __restrict__ b1,
    const float* __restrict__ w2, const float* __restrict__ b2,
    const float* __restrict__ w3, const float* __restrict__ b3,
    const float* __restrict__ fcw, const float* __restrict__ fcb,
    float* __restrict__ out, int n)
{
    const int tid = blockIdx.x * blockDim.x + threadIdx.x;
    const int gid = tid >> 4;              // group of 16 lanes = 2 elements
    const int m   = tid & 15;
    const int eA  = 2 * gid, eB = 2 * gid + 1;
    if (eA >= n) return;
    const bool hasB = (eB < n);

    // Butterfly arrival permutation: slot i sources lane m ^ P[i].
    const int P[16] = {0,1,2,3, 7,6,5,4, 15,14,13,12, 8,9,10,11};

    // ---- weight slices (lane owns cols 2m, 2m+1), pre-permuted by P ----
    const v2f* w2v = (const v2f*)w2;       // (32,32): w2v[r*16+c2] = w2[r][2c2:2c2+2]
    v2f w2a[16], w2b[16];                  // slot i: rows 2j, 2j+1 (j = m^P[i]), own col pair
#pragma unroll
    for (int i = 0; i < 16; ++i) {
        int j = m ^ P[i];
        w2a[i] = w2v[(2*j    ) * 16 + m];
        w2b[i] = w2v[(2*j + 1) * 16 + m];
    }
    const v2f* w1v = (const v2f*)w1;       // (3,32)
    v2f w1p0 = w1v[0*16 + m], w1p1 = w1v[1*16 + m], w1p2 = w1v[2*16 + m];
    v2f b1p  = ((const v2f*)b1)[m];
    v2f b2p  = ((const v2f*)b2)[m];
    v2f w3p0; w3p0.x = w3[(2*m)*2+0]; w3p0.y = w3[(2*m+1)*2+0];  // rows 2m,2m+1 -> out0
    v2f w3p1; w3p1.x = w3[(2*m)*2+1]; w3p1.y = w3[(2*m+1)*2+1];  // rows 2m,2m+1 -> out1
    v2f b3c  = { b3[0], b3[1] };

    // Pin weights in VGPRs (r3 evidence: prevents in-loop rematerialization).
#pragma unroll
    for (int i = 0; i < 16; ++i) { asm volatile("" : "+v"(w2a[i]), "+v"(w2b[i])); }
    asm volatile("" : "+v"(w1p0), "+v"(w1p1), "+v"(w1p2), "+v"(b1p), "+v"(b2p));
    asm volatile("" : "+v"(w3p0), "+v"(w3p1));

    // ---- ODE state: elements A/B in pk halves ----
    v2f xA = ((const v2f*)x)[eA];
    v2f xB = hasB ? ((const v2f*)x)[eB] : xA;
    v2f y0pk; y0pk.x = xA.x; y0pk.y = xB.x;
    v2f y1pk; y1pk.x = xA.y; y1pk.y = xB.y;
    float TA = fminf(samples[eA], 50.0f);
    float TB = hasB ? fminf(samples[eB], 50.0f) : TA;
    v2f tpk = splat(0.0f);
    v2f hpk = splat(0.05f);

    // f(t, y) for both packed elements; all cross-lane traffic is DPP.
    auto f_eval = [&](v2f tt, v2f z0, v2f z1, v2f& o0, v2f& o1) {
        // layer 1: own 2 cols, both elements packed
        v2f h0 = vrelu(vfma(tt, slo(w1p0), vfma(z0, slo(w1p1), vfma(z1, slo(w1p2), slo(b1p)))));
        v2f h1 = vrelu(vfma(tt, shi(w1p0), vfma(z0, shi(w1p1), vfma(z1, shi(w1p2), shi(b1p)))));

        // 4-stage involution butterfly all-gather (60 v_mov_dpp)
        v2f g0[16], g1[16];
        g0[0] = h0; g1[0] = h1;
#define BF(d,s,C) g0[d].x=dppf<C>(g0[s].x); g0[d].y=dppf<C>(g0[s].y); \
                  g1[d].x=dppf<C>(g1[s].x); g1[d].y=dppf<C>(g1[s].y);
        BF(1,0,0xB1)                                       // xor1
        BF(2,0,0x4E)  BF(3,1,0x4E)                         // xor2
        BF(4,0,0x141) BF(5,1,0x141) BF(6,2,0x141) BF(7,3,0x141)   // xor7
        BF(8,0,0x140) BF(9,1,0x140) BF(10,2,0x140) BF(11,3,0x140) // xor15
        BF(12,4,0x140) BF(13,5,0x140) BF(14,6,0x140) BF(15,7,0x140)
#undef BF

        // layer 2: 4 independent packed chains, weights pre-permuted
        v2f a0 = slo(b2p), a1 = shi(b2p), c0 = splat(0.0f), c1 = splat(0.0f);
#pragma unroll
        for (int i = 0; i < 16; ++i) {
            a0 = vfma(g0[i], slo(w2a[i]), a0);
            a1 = vfma(g0[i], shi(w2a[i]), a1);
            c0 = vfma(g1[i], slo(w2b[i]), c0);
            c1 = vfma(g1[i], shi(w2b[i]), c1);
        }
        v2f h2a = vrelu(a0 + c0);            // own col 2m   (pk elems)
        v2f h2b = vrelu(a1 + c1);            // own col 2m+1

        // layer 3: own 2 rows, then 16-lane DPP all-reduce (VALU pipe)
        v2f p0 = vfma(h2a, slo(w3p0), h2b * shi(w3p0));
        v2f p1 = vfma(h2a, slo(w3p1), h2b * shi(w3p1));
        p0 = dpp_allreduce16(p0);
        p1 = dpp_allreduce16(p1);
        o0 = p0 + slo(b3c);
        o1 = p1 + shi(b3c);
    };

    // FSAL: initial k1; thereafter k1 = accept ? k7 : k1 (per half, exact).
    v2f k10, k11; f_eval(tpk, y0pk, y1pk, k10, k11);

    for (int s = 0; s < MAXS; ++s) {
        float remA = TA - tpk.x, remB = TB - tpk.y;
        bool actA = remA > 1e-8f;
        bool actB = hasB && (remB > 1e-8f);
        if (!actA && !actB) break;
        float hsA = actA ? fminf(hpk.x, remA) : 0.0f;
        float hsB = actB ? fminf(hpk.y, remB) : 0.0f;
        v2f hb; hb.x = hsA; hb.y = hsB;

        v2f k20,k21,k30,k31,k40,k41,k50,k51,k60,k61,k70,k71,u0,u1,y50,y51;

        u0 = vfma(hb, splat(0.2f) * k10, y0pk);
        u1 = vfma(hb, splat(0.2f) * k11, y1pk);
        f_eval(tpk + hb * splat(0.2f), u0, u1, k20, k21);

        u0 = vfma(hb, vfma(splat((float)(3.0/40.0)), k10, splat((float)(9.0/40.0)) * k20), y0pk);
        u1 = vfma(hb, vfma(splat((float)(3.0/40.0)), k11, splat((float)(9.0/40.0)) * k21), y1pk);
        f_eval(tpk + hb * splat(0.3f), u0, u1, k30, k31);

        u0 = vfma(hb, vfma(splat((float)(44.0/45.0)), k10,
                  vfma(splat((float)(-56.0/15.0)), k20, splat((float)(32.0/9.0)) * k30)), y0pk);
        u1 = vfma(hb, vfma(splat((float)(44.0/45.0)), k11,
                  vfma(splat((float)(-56.0/15.0)), k21, splat((float)(32.0/9.0)) * k31)), y1pk);
        f_eval(tpk + hb * splat(0.8f), u0, u1, k40, k41);

        u0 = vfma(hb, vfma(splat((float)(19372.0/6561.0)), k10,
                  vfma(splat((float)(-25360.0/2187.0)), k20,
                  vfma(splat((float)(64448.0/6561.0)), k30,
                       splat((float)(-212.0/729.0)) * k40))), y0pk);
        u1 = vfma(hb, vfma(splat((float)(19372.0/6561.0)), k11,
                  vfma(splat((float)(-25360.0/2187.0)), k21,
                  vfma(splat((float)(64448.0/6561.0)), k31,
                       splat((float)(-212.0/729.0)) * k41))), y1pk);
        f_eval(tpk + hb * splat((float)(8.0/9.0)), u0, u1, k50, k51);

        u0 = vfma(hb, vfma(splat((float)(9017.0/3168.0)), k10,
                  vfma(splat((float)(-355.0/33.0)), k20,
                  vfma(splat((float)(46732.0/5247.0)), k30,
                  vfma(splat((float)(49.0/176.0)), k40,
                       splat((float)(-5103.0/18656.0)) * k50)))), y0pk);
        u1 = vfma(hb, vfma(splat((float)(9017.0/3168.0)), k11,
                  vfma(splat((float)(-355.0/33.0)), k21,
                  vfma(splat((float)(46732.0/5247.0)), k31,
                  vfma(splat((float)(49.0/176.0)), k41,
                       splat((float)(-5103.0/18656.0)) * k51)))), y1pk);
        f_eval(tpk + hb, u0, u1, k60, k61);

        y50 = vfma(hb, vfma(splat((float)(35.0/384.0)), k10,
                   vfma(splat((float)(500.0/1113.0)), k30,
                   vfma(splat((float)(125.0/192.0)), k40,
                   vfma(splat((float)(-2187.0/6784.0)), k50,
                        splat((float)(11.0/84.0)) * k60)))), y0pk);
        y51 = vfma(hb, vfma(splat((float)(35.0/384.0)), k11,
                   vfma(splat((float)(500.0/1113.0)), k31,
                   vfma(splat((float)(125.0/192.0)), k41,
                   vfma(splat((float)(-2187.0/6784.0)), k51,
                        splat((float)(11.0/84.0)) * k61)))), y1pk);
        f_eval(tpk + hb, y50, y51, k70, k71);

        v2f err0 = hb * vfma(splat((float)(71.0/57600.0)), k10,
                        vfma(splat((float)(-71.0/16695.0)), k30,
                        vfma(splat((float)(71.0/1920.0)), k40,
                        vfma(splat((float)(-17253.0/339200.0)), k50,
                        vfma(splat((float)(22.0/525.0)), k60,
                             splat((float)(-1.0/40.0)) * k70)))));
        v2f err1 = hb * vfma(splat((float)(71.0/57600.0)), k11,
                        vfma(splat((float)(-71.0/16695.0)), k31,
                        vfma(splat((float)(71.0/1920.0)), k41,
                        vfma(splat((float)(-17253.0/339200.0)), k51,
                        vfma(splat((float)(22.0/525.0)), k61,
                             splat((float)(-1.0/40.0)) * k71)))));

        v2f sc0 = vfma(splat(0.01f),
                  __builtin_elementwise_max(__builtin_elementwise_abs(y0pk),
                                            __builtin_elementwise_abs(y50)), splat(0.01f));
        v2f sc1 = vfma(splat(0.01f),
                  __builtin_elementwise_max(__builtin_elementwise_abs(y1pk),
                                            __builtin_elementwise_abs(y51)), splat(0.01f));
        v2f r0 = err0 / sc0;
        v2f r1 = err1 / sc1;

        float enA = sqrtf(0.5f * (r0.x * r0.x + r1.x * r1.x));
        float enB = sqrtf(0.5f * (r0.y * r0.y + r1.y * r1.y));
        float facA = fminf(fmaxf(0.9f * exp2f(-0.2f * log2f(fmaxf(enA, 1e-10f))), 0.2f), 10.0f);
        float facB = fminf(fmaxf(0.9f * exp2f(-0.2f * log2f(fmaxf(enB, 1e-10f))), 0.2f), 10.0f);

        bool accA = actA && (enA <= 1.0f);
        bool accB = actB && (enB <= 1.0f);
        if (accA) { tpk.x += hsA; y0pk.x = y50.x; y1pk.x = y51.x; k10.x = k70.x; k11.x = k71.x; }
        if (accB) { tpk.y += hsB; y0pk.y = y50.y; y1pk.y = y51.y; k10.y = k70.y; k11.y = k71.y; }
        if (actA) hpk.x = hsA * facA;
        if (actB) hpk.y = hsB * facB;
    }

    // final head: y @ fc_w (2x10) + fc_b, per element half
    if (m < 10) {
        out[10 * eA + m] = fmaf(y0pk.x, fcw[m], fmaf(y1pk.x, fcw[10 + m], fcb[m]));
        if (hasB)
            out[10 * eB + m] = fmaf(y0pk.y, fcw[m], fmaf(y1pk.y, fcw[10 + m], fcb[m]));
    }
}

extern "C" void kernel_launch(void* const* d_in, const int* in_sizes, int n_in,
                              void* d_out, int out_size, void* d_ws, size_t ws_size,
                              hipStream_t stream) {
    const float* x   = (const float*)d_in[0];
    const float* sm  = (const float*)d_in[1];
    const float* w1  = (const float*)d_in[2];
    const float* b1  = (const float*)d_in[3];
    const float* w2  = (const float*)d_in[4];
    const float* b2  = (const float*)d_in[5];
    const float* w3  = (const float*)d_in[6];
    const float* b3  = (const float*)d_in[7];
    const float* fcw = (const float*)d_in[8];
    const float* fcb = (const float*)d_in[9];
    // d_in[10..15] = enc_* : dead code in the reference, unused.
    float* out = (float*)d_out;

    int n = in_sizes[1];                            // B
    const int block = 256;
    long long groups  = (n + 1) / 2;                // 2 elements per group
    long long threads = groups * 16;                // 16 lanes per group
    int grid = (int)((threads + block - 1) / block);
    node_kernel<<<grid, block, 0, stream>>>(x, sm, w1, b1, w2, b2, w3, b3,
                                            fcw, fcb, out, n);
}

// Round 9
// 112.094 us; speedup vs baseline: 1.0209x; 1.0209x over previous
//
#include <hip/hip_runtime.h>
#include <math.h>

// Neural-ODE RK45 — round 9: 32 lanes per element, occupancy-first.
// Cross-round invariant (r2-r8): all structures land at 30-46 us with
// VALUBusy <=28% and measured residency only ~1.4-2 waves/SIMD — the
// serial chain per eval is exposed and the step-count tail drains the
// grid. This round shrinks the per-wave footprint so the machine can
// actually fill: lane l (=tid&31) owns hidden col l -> w2 slice is
// 32 VGPRs (not 128), total ~100 VGPR -> 4-5 resident waves/SIMD under
// __launch_bounds__(256,4). 16384 one-element groups -> 2048 blocks
// (8 waves/SIMD launched): the HW dispatcher backfills as blocks finish,
// and wave-max is over just 2 elements/wave (minimal tail).
// Gather: LDS broadcast (1x ds_write_b32 + 8x broadcast ds_read_b128,
// conflict-free); 32-lane all-reduce: 4 involutive DPP stages within the
// 16-lane rows + ds_swizzle xor16 across rows (swizzle domain = 32 lanes,
// so a masked-off sibling group never feeds an active one). FSAL kept.

#define MAXS 96

typedef float v2f __attribute__((ext_vector_type(2)));

static __device__ __forceinline__ v2f splat(float s){ v2f v; v.x=s; v.y=s; return v; }
static __device__ __forceinline__ v2f vfma(v2f a, v2f b, v2f c){ return __builtin_elementwise_fma(a,b,c); }
static __device__ __forceinline__ v2f vrelu(v2f a){ return __builtin_elementwise_max(a, splat(0.0f)); }

template<int CTRL>
static __device__ __forceinline__ float dppf(float x){
    return __int_as_float(__builtin_amdgcn_update_dpp(0, __float_as_int(x), CTRL, 0xF, 0xF, false));
}
static __device__ __forceinline__ float swz16(float x){
    // BitMode: xor_mask=16, and_mask=0x1f -> exchange halves of each 32-lane group
    return __int_as_float(__builtin_amdgcn_ds_swizzle(__float_as_int(x), 0x401F));
}
// 32-lane all-reduce sum; stages are involutions -> bitwise-uniform result.
static __device__ __forceinline__ v2f allreduce32(v2f p){
    p.x += dppf<0xB1>(p.x);  p.y += dppf<0xB1>(p.y);   // xor1
    p.x += dppf<0x4E>(p.x);  p.y += dppf<0x4E>(p.y);   // xor2
    p.x += dppf<0x141>(p.x); p.y += dppf<0x141>(p.y);  // half-row mirror
    p.x += dppf<0x140>(p.x); p.y += dppf<0x140>(p.y);  // row mirror (16-lane sum)
    p.x += swz16(p.x);       p.y += swz16(p.y);        // cross-row xor16
    return p;
}

__global__ __launch_bounds__(256, 4) void node_kernel(
    const float* __restrict__ x, const float* __restrict__ samples,
    const float* __restrict__ w1, const float* __restrict__ b1,
    const float* __restrict__ w2, const float* __restrict__ b2,
    const float* __restrict__ w3, const float* __restrict__ b3,
    const float* __restrict__ fcw, const float* __restrict__ fcb,
    float* __restrict__ out, int n)
{
    const int tid  = blockIdx.x * blockDim.x + threadIdx.x;
    const int elem = tid >> 5;           // one element per 32-lane group
    const int m    = tid & 31;
    if (elem >= n) return;

    // 8 groups/block, 36-float (144 B) slots; write banks distinct within
    // a group, 2-way aliasing between the wave's two groups (free).
    __shared__ float lds[8 * 36];
    float* slot = &lds[(threadIdx.x >> 5) * 36];

    // ---- weight slices: lane owns hidden col m ----
    float w2c[32];                        // w2[j][m], j = 0..31
#pragma unroll
    for (int j = 0; j < 32; ++j) w2c[j] = w2[j * 32 + m];
    float w1c0 = w1[ 0 + m], w1c1 = w1[32 + m], w1c2 = w1[64 + m];
    float b1c  = b1[m], b2c = b2[m];
    v2f   w3c; w3c.x = w3[2*m + 0]; w3c.y = w3[2*m + 1];   // row m of w3
    v2f   b3c; b3c.x = b3[0]; b3c.y = b3[1];

    // Pin in VGPRs (r3 evidence: prevents in-loop rematerialization).
#pragma unroll
    for (int j = 0; j < 32; ++j) { asm volatile("" : "+v"(w2c[j])); }
    asm volatile("" : "+v"(w1c0), "+v"(w1c1), "+v"(w1c2), "+v"(b1c), "+v"(b2c));
    asm volatile("" : "+v"(w3c));

    v2f y = ((const v2f*)x)[elem];        // ODE state (y0, y1)
    float T = fminf(samples[elem], 50.0f);
    float t = 0.0f;
    float h = 0.05f;

    // f(t, y) -> v2f, cooperative across the 32-lane group
    auto f_eval = [&](float tt, v2f z) -> v2f {
        // layer 1: own col, relu (3 FMA)
        float hv = fmaxf(fmaf(tt, w1c0, fmaf(z.x, w1c1, fmaf(z.y, w1c2, b1c))), 0.0f);

        // publish own h1; same-wave DS ops are ordered (no barrier)
        slot[m] = hv;

        // broadcast-read all 32 h1 (8x ds_read_b128, same addr in group)
        const float4* gp = (const float4*)slot;

        // layer 2: own col, 4 independent chains of 8
        float a0 = b2c, a1 = 0.0f, a2 = 0.0f, a3 = 0.0f;
#pragma unroll
        for (int j = 0; j < 8; j += 4) {
            float4 r0 = gp[j], r1 = gp[j+1], r2 = gp[j+2], r3 = gp[j+3];
            a0 = fmaf(r0.x, w2c[4*j +  0], a0); a1 = fmaf(r0.y, w2c[4*j +  1], a1);
            a2 = fmaf(r0.z, w2c[4*j +  2], a2); a3 = fmaf(r0.w, w2c[4*j +  3], a3);
            a0 = fmaf(r1.x, w2c[4*j +  4], a0); a1 = fmaf(r1.y, w2c[4*j +  5], a1);
            a2 = fmaf(r1.z, w2c[4*j +  6], a2); a3 = fmaf(r1.w, w2c[4*j +  7], a3);
            a0 = fmaf(r2.x, w2c[4*j +  8], a0); a1 = fmaf(r2.y, w2c[4*j +  9], a1);
            a2 = fmaf(r2.z, w2c[4*j + 10], a2); a3 = fmaf(r2.w, w2c[4*j + 11], a3);
            a0 = fmaf(r3.x, w2c[4*j + 12], a0); a1 = fmaf(r3.y, w2c[4*j + 13], a1);
            a2 = fmaf(r3.z, w2c[4*j + 14], a2); a3 = fmaf(r3.w, w2c[4*j + 15], a3);
        }
        float h2 = fmaxf((a0 + a1) + (a2 + a3), 0.0f);

        // layer 3: own row (2 FMAs packed) + 32-lane all-reduce
        v2f p = splat(h2) * w3c;
        p = allreduce32(p);
        return p + b3c;
    };

    // FSAL: initial k1; thereafter k1 = accept ? k7 : k1 (bitwise exact).
    v2f k1 = f_eval(0.0f, y);

    for (int s = 0; s < MAXS; ++s) {
        float rem = T - t;
        if (!(rem > 1e-8f)) break;           // state frozen from here on
        float hs = fminf(h, rem);
        v2f hb = splat(hs);

        v2f k2 = f_eval(t + hs * 0.2f, vfma(hb, splat(0.2f) * k1, y));
        v2f k3 = f_eval(t + hs * 0.3f,
                 vfma(hb, vfma(splat((float)(3.0/40.0)), k1, splat((float)(9.0/40.0)) * k2), y));
        v2f k4 = f_eval(t + hs * 0.8f,
                 vfma(hb, vfma(splat((float)(44.0/45.0)), k1,
                          vfma(splat((float)(-56.0/15.0)), k2, splat((float)(32.0/9.0)) * k3)), y));
        v2f k5 = f_eval(t + hs * (float)(8.0/9.0),
                 vfma(hb, vfma(splat((float)(19372.0/6561.0)), k1,
                          vfma(splat((float)(-25360.0/2187.0)), k2,
                          vfma(splat((float)(64448.0/6561.0)), k3,
                               splat((float)(-212.0/729.0)) * k4))), y));
        v2f k6 = f_eval(t + hs,
                 vfma(hb, vfma(splat((float)(9017.0/3168.0)), k1,
                          vfma(splat((float)(-355.0/33.0)), k2,
                          vfma(splat((float)(46732.0/5247.0)), k3,
                          vfma(splat((float)(49.0/176.0)), k4,
                               splat((float)(-5103.0/18656.0)) * k5)))), y));
        v2f y5 = vfma(hb, vfma(splat((float)(35.0/384.0)), k1,
                          vfma(splat((float)(500.0/1113.0)), k3,
                          vfma(splat((float)(125.0/192.0)), k4,
                          vfma(splat((float)(-2187.0/6784.0)), k5,
                               splat((float)(11.0/84.0)) * k6)))), y);
        v2f k7 = f_eval(t + hs, y5);

        v2f err = hb * vfma(splat((float)(71.0/57600.0)), k1,
                       vfma(splat((float)(-71.0/16695.0)), k3,
                       vfma(splat((float)(71.0/1920.0)), k4,
                       vfma(splat((float)(-17253.0/339200.0)), k5,
                       vfma(splat((float)(22.0/525.0)), k6,
                            splat((float)(-1.0/40.0)) * k7)))));

        v2f sc = vfma(splat(0.01f),
                 __builtin_elementwise_max(__builtin_elementwise_abs(y),
                                           __builtin_elementwise_abs(y5)), splat(0.01f));
        v2f r = err / sc;
        float en = sqrtf(0.5f * (r.x * r.x + r.y * r.y));

        float fac = fminf(fmaxf(0.9f * exp2f(-0.2f * log2f(fmaxf(en, 1e-10f))), 0.2f), 10.0f);

        bool accept = (en <= 1.0f);
        if (accept) { t += hs; y = y5; }
        k1 = accept ? k7 : k1;               // FSAL (exact)
        h = hs * fac;
    }

    // final head: y @ fc_w (2x10) + fc_b; all 32 lanes hold identical y.
    if (m < 10) {
        out[10 * elem + m] = fmaf(y.x, fcw[m], fmaf(y.y, fcw[10 + m], fcb[m]));
    }
}

extern "C" void kernel_launch(void* const* d_in, const int* in_sizes, int n_in,
                              void* d_out, int out_size, void* d_ws, size_t ws_size,
                              hipStream_t stream) {
    const float* x   = (const float*)d_in[0];
    const float* sm  = (const float*)d_in[1];
    const float* w1  = (const float*)d_in[2];
    const float* b1  = (const float*)d_in[3];
    const float* w2  = (const float*)d_in[4];
    const float* b2  = (const float*)d_in[5];
    const float* w3  = (const float*)d_in[6];
    const float* b3  = (const float*)d_in[7];
    const float* fcw = (const float*)d_in[8];
    const float* fcb = (const float*)d_in[9];
    // d_in[10..15] = enc_* : dead code in the reference, unused.
    float* out = (float*)d_out;

    int n = in_sizes[1];                         // B
    const int block = 256;                       // 8 groups/block
    long long threads = (long long)n * 32;       // 32 lanes per element
    int grid = (int)((threads + block - 1) / block);  // 2048 blocks
    node_kernel<<<grid, block, 0, stream>>>(x, sm, w1, b1, w2, b2, w3, b3,
                                            fcw, fcb, out, n);
}

// Round 10
// 102.561 us; speedup vs baseline: 1.1158x; 1.0930x over previous
//
#include <hip/hip_runtime.h>
#include <math.h>

// Neural-ODE RK45 — round 10: 8 lanes/element, ZERO-DS f_eval.
// Invariant from r2-r9: LDS delivery is charged per-lane (broadcast or not)
// -> every shape that pulled the 32-float h1 through LDS paid ~64-128 B/lane
// /eval and plateaued at 30-40 us. This round removes DS from the eval loop
// entirely using the discovery that DPP row_half_mirror (0x141) is xor7
// within each aligned 8-lane half — a cross-quad involution on the VALU pipe:
//  - layer-2 is K-SPLIT BY QUAD: lane (q,i) accumulates its quad's 16 rows
//    for 8 cols (its own L3 half 'accMine' + partner's half 'accOther');
//    gather of the quad's 16 h1 = 16 quad_perm DPP broadcasts (no DS).
//  - cross-quad exchange: full_mine = accMine + dpp0x141(accOther) — the
//    xor7 partner's accOther is exactly my 4 cols. 4 DPP + 2 pk-add.
//  - 8-lane allreduce: xor1(0xB1), xor2(0x4E), xor7(0x141) — all DPP.
// Col blocks pair under xor7: lane m handles block b = m<4 ? m : 7-m,
// half q; rows 8b+4q..+4 of w3. Bias b2 folded into accMine init (each col's
// owner adds it exactly once). FSAL, pinning, exp2/log2 controller kept.
// 131072 threads = 2048 waves = 2/SIMD; ~205 VGPR under (256,2).

#define MAXS 96

typedef float v2f __attribute__((ext_vector_type(2)));

static __device__ __forceinline__ v2f splat(float s){ v2f v; v.x=s; v.y=s; return v; }
static __device__ __forceinline__ v2f vfma(v2f a, v2f b, v2f c){ return __builtin_elementwise_fma(a,b,c); }
static __device__ __forceinline__ v2f vrelu(v2f a){ return __builtin_elementwise_max(a, splat(0.0f)); }

template<int CTRL>
static __device__ __forceinline__ float dppf(float x){
    return __int_as_float(__builtin_amdgcn_update_dpp(0, __float_as_int(x), CTRL, 0xF, 0xF, false));
}
// 8-lane all-reduce, all on the VALU pipe (involutions: xor1, xor2, xor7).
static __device__ __forceinline__ v2f dpp_allreduce8(v2f p){
    p.x += dppf<0xB1>(p.x);  p.y += dppf<0xB1>(p.y);   // quad_perm xor1
    p.x += dppf<0x4E>(p.x);  p.y += dppf<0x4E>(p.y);   // quad_perm xor2
    p.x += dppf<0x141>(p.x); p.y += dppf<0x141>(p.y);  // row_half_mirror = xor7
    return p;
}

__global__ __launch_bounds__(256, 2) void node_kernel(
    const float* __restrict__ x, const float* __restrict__ samples,
    const float* __restrict__ w1, const float* __restrict__ b1,
    const float* __restrict__ w2, const float* __restrict__ b2,
    const float* __restrict__ w3, const float* __restrict__ b3,
    const float* __restrict__ fcw, const float* __restrict__ fcb,
    float* __restrict__ out, int n)
{
    const int tid  = blockIdx.x * blockDim.x + threadIdx.x;
    const int elem = tid >> 3;
    const int m    = tid & 7;            // lane in 8-lane group
    if (elem >= n) return;
    const int q = m >> 2;                // quad (0/1)
    const int b = (m < 4) ? m : (7 - m); // col block, pairs under xor7
    const int mineC  = 8 * b + 4 * q;        // my 4 L3 cols
    const int otherC = 8 * b + 4 * (1 - q);  // partner's 4 cols

    // ---- per-lane weight slices (loaded once, pinned) ----
    const v2f* w2v = (const v2f*)w2;     // (32,32): w2v[r*16 + c/2]
    v2f w2m[32], w2o[32];                // rows 16q..16q+16; [k*2+p]
#pragma unroll
    for (int k = 0; k < 16; ++k) {
#pragma unroll
        for (int p = 0; p < 2; ++p) {
            w2m[k*2+p] = w2v[(16*q + k) * 16 + mineC/2  + p];
            w2o[k*2+p] = w2v[(16*q + k) * 16 + otherC/2 + p];
        }
    }
    // layer 1: lane computes h1[4m..4m+4) (pairs A, B)
    float4 w1f0 = ((const float4*)w1)[0*8 + m];
    float4 w1f1 = ((const float4*)w1)[1*8 + m];
    float4 w1f2 = ((const float4*)w1)[2*8 + m];
    float4 b1f  = ((const float4*)b1)[m];
    v2f w1_0A = {w1f0.x, w1f0.y}, w1_0B = {w1f0.z, w1f0.w};
    v2f w1_1A = {w1f1.x, w1f1.y}, w1_1B = {w1f1.z, w1f1.w};
    v2f w1_2A = {w1f2.x, w1f2.y}, w1_2B = {w1f2.z, w1f2.w};
    v2f b1A   = {b1f.x,  b1f.y }, b1B   = {b1f.z,  b1f.w };
    // bias for my 4 cols (added exactly once: by the col's owner)
    const v2f* b2v = (const v2f*)b2;
    v2f b2m0 = b2v[mineC/2 + 0], b2m1 = b2v[mineC/2 + 1];
    // w3 rows mineC..mineC+4 (each row r -> (w3[r][0], w3[r][1]))
    const v2f* w3v = (const v2f*)w3;
    v2f w3r0 = w3v[mineC+0], w3r1 = w3v[mineC+1], w3r2 = w3v[mineC+2], w3r3 = w3v[mineC+3];
    v2f b3c; b3c.x = b3[0]; b3c.y = b3[1];

#pragma unroll
    for (int k = 0; k < 32; ++k) { asm volatile("" : "+v"(w2m[k]), "+v"(w2o[k])); }
    asm volatile("" : "+v"(w1_0A), "+v"(w1_0B), "+v"(w1_1A), "+v"(w1_1B));
    asm volatile("" : "+v"(w1_2A), "+v"(w1_2B), "+v"(b1A), "+v"(b1B));
    asm volatile("" : "+v"(b2m0), "+v"(b2m1));
    asm volatile("" : "+v"(w3r0), "+v"(w3r1), "+v"(w3r2), "+v"(w3r3));

    v2f y = ((const v2f*)x)[elem];       // ODE state (y0, y1)
    float T = fminf(samples[elem], 50.0f);
    float t = 0.0f;
    float h = 0.05f;

    // f(t, y): zero DS — gather/exchange/reduce all DPP.
    auto f_eval = [&](float tt, v2f z) -> v2f {
        // layer 1: own 4 cols
        v2f hA = vrelu(vfma(splat(tt), w1_0A, vfma(splat(z.x), w1_1A, vfma(splat(z.y), w1_2A, b1A))));
        v2f hB = vrelu(vfma(splat(tt), w1_0B, vfma(splat(z.x), w1_1B, vfma(splat(z.y), w1_2B, b1B))));

        // in-quad all-gather of the quad's 16 h1 (rows 16q..16q+16 of w2)
        float g[16];
        g[ 0]=dppf<0x00>(hA.x); g[ 1]=dppf<0x00>(hA.y); g[ 2]=dppf<0x00>(hB.x); g[ 3]=dppf<0x00>(hB.y);
        g[ 4]=dppf<0x55>(hA.x); g[ 5]=dppf<0x55>(hA.y); g[ 6]=dppf<0x55>(hB.x); g[ 7]=dppf<0x55>(hB.y);
        g[ 8]=dppf<0xAA>(hA.x); g[ 9]=dppf<0xAA>(hA.y); g[10]=dppf<0xAA>(hB.x); g[11]=dppf<0xAA>(hB.y);
        g[12]=dppf<0xFF>(hA.x); g[13]=dppf<0xFF>(hA.y); g[14]=dppf<0xFF>(hB.x); g[15]=dppf<0xFF>(hB.y);

        // layer 2, K-split: my quad's 16 rows x 8 cols (4 mine + 4 other)
        v2f am0 = b2m0, am1 = b2m1, ao0 = splat(0.0f), ao1 = splat(0.0f);
#pragma unroll
        for (int k = 0; k < 16; ++k) {
            v2f gk = splat(g[k]);
            am0 = vfma(gk, w2m[k*2+0], am0);
            am1 = vfma(gk, w2m[k*2+1], am1);
            ao0 = vfma(gk, w2o[k*2+0], ao0);
            ao1 = vfma(gk, w2o[k*2+1], ao1);
        }
        // cross-quad exchange: partner's accOther = my cols (xor7 DPP)
        v2f x0, x1;
        x0.x = dppf<0x141>(ao0.x); x0.y = dppf<0x141>(ao0.y);
        x1.x = dppf<0x141>(ao1.x); x1.y = dppf<0x141>(ao1.y);
        v2f h2a = vrelu(am0 + x0);       // my cols mineC, mineC+1
        v2f h2b = vrelu(am1 + x1);       // my cols mineC+2, mineC+3

        // layer 3: my 4 rows -> 2 outputs, then 8-lane DPP all-reduce
        v2f p = vfma(splat(h2a.x), w3r0,
                vfma(splat(h2a.y), w3r1,
                vfma(splat(h2b.x), w3r2, splat(h2b.y) * w3r3)));
        p = dpp_allreduce8(p);
        return p + b3c;
    };

    // FSAL: initial k1; thereafter k1 = accept ? k7 : k1 (bitwise exact).
    v2f k1 = f_eval(0.0f, y);

    for (int s = 0; s < MAXS; ++s) {
        float rem = T - t;
        if (!(rem > 1e-8f)) break;           // state frozen from here on
        float hs = fminf(h, rem);
        v2f hb = splat(hs);

        v2f k2 = f_eval(t + hs * 0.2f, vfma(hb, splat(0.2f) * k1, y));
        v2f k3 = f_eval(t + hs * 0.3f,
                 vfma(hb, vfma(splat((float)(3.0/40.0)), k1, splat((float)(9.0/40.0)) * k2), y));
        v2f k4 = f_eval(t + hs * 0.8f,
                 vfma(hb, vfma(splat((float)(44.0/45.0)), k1,
                          vfma(splat((float)(-56.0/15.0)), k2, splat((float)(32.0/9.0)) * k3)), y));
        v2f k5 = f_eval(t + hs * (float)(8.0/9.0),
                 vfma(hb, vfma(splat((float)(19372.0/6561.0)), k1,
                          vfma(splat((float)(-25360.0/2187.0)), k2,
                          vfma(splat((float)(64448.0/6561.0)), k3,
                               splat((float)(-212.0/729.0)) * k4))), y));
        v2f k6 = f_eval(t + hs,
                 vfma(hb, vfma(splat((float)(9017.0/3168.0)), k1,
                          vfma(splat((float)(-355.0/33.0)), k2,
                          vfma(splat((float)(46732.0/5247.0)), k3,
                          vfma(splat((float)(49.0/176.0)), k4,
                               splat((float)(-5103.0/18656.0)) * k5)))), y));
        v2f y5 = vfma(hb, vfma(splat((float)(35.0/384.0)), k1,
                          vfma(splat((float)(500.0/1113.0)), k3,
                          vfma(splat((float)(125.0/192.0)), k4,
                          vfma(splat((float)(-2187.0/6784.0)), k5,
                               splat((float)(11.0/84.0)) * k6)))), y);
        v2f k7 = f_eval(t + hs, y5);

        v2f err = hb * vfma(splat((float)(71.0/57600.0)), k1,
                       vfma(splat((float)(-71.0/16695.0)), k3,
                       vfma(splat((float)(71.0/1920.0)), k4,
                       vfma(splat((float)(-17253.0/339200.0)), k5,
                       vfma(splat((float)(22.0/525.0)), k6,
                            splat((float)(-1.0/40.0)) * k7)))));

        v2f sc = vfma(splat(0.01f),
                 __builtin_elementwise_max(__builtin_elementwise_abs(y),
                                           __builtin_elementwise_abs(y5)), splat(0.01f));
        v2f r = err / sc;
        float en = sqrtf(0.5f * (r.x * r.x + r.y * r.y));

        float fac = fminf(fmaxf(0.9f * exp2f(-0.2f * log2f(fmaxf(en, 1e-10f))), 0.2f), 10.0f);

        bool accept = (en <= 1.0f);
        if (accept) { t += hs; y = y5; }
        k1 = accept ? k7 : k1;               // FSAL (exact)
        h = hs * fac;
    }

    // final head: y @ fc_w (2x10) + fc_b; all 8 lanes hold identical y.
    out[10 * elem + m] = fmaf(y.x, fcw[m], fmaf(y.y, fcw[10 + m], fcb[m]));
    if (m < 2) {
        int c = 8 + m;
        out[10 * elem + c] = fmaf(y.x, fcw[c], fmaf(y.y, fcw[10 + c], fcb[c]));
    }
}

extern "C" void kernel_launch(void* const* d_in, const int* in_sizes, int n_in,
                              void* d_out, int out_size, void* d_ws, size_t ws_size,
                              hipStream_t stream) {
    const float* x   = (const float*)d_in[0];
    const float* sm  = (const float*)d_in[1];
    const float* w1  = (const float*)d_in[2];
    const float* b1  = (const float*)d_in[3];
    const float* w2  = (const float*)d_in[4];
    const float* b2  = (const float*)d_in[5];
    const float* w3  = (const float*)d_in[6];
    const float* b3  = (const float*)d_in[7];
    const float* fcw = (const float*)d_in[8];
    const float* fcb = (const float*)d_in[9];
    // d_in[10..15] = enc_* : dead code in the reference, unused.
    float* out = (float*)d_out;

    int n = in_sizes[1];                        // B
    const int block = 256;
    long long threads = (long long)n * 8;       // 8 lanes per element
    int grid = (int)((threads + block - 1) / block);   // 512 blocks
    node_kernel<<<grid, block, 0, stream>>>(x, sm, w1, b1, w2, b2, w3, b3,
                                            fcw, fcb, out, n);
}